// Round 4
// baseline (86.605 us; speedup 1.0000x reference)
//
#include <hip/hip_runtime.h>

// WeightedCCEDiceLossWithSoftmax — fused single-pass reduction.
// Round 4: one-shot maximal MLP. Each thread owns 4 ADJACENT samples
// (128B/array), all 16 float4 loads issued before any compute; grid sized so
// the main loop executes exactly once (B = 4096*256*4). Register nibble
// counters + wave shuffle reduction (no per-sample LDS atomics).
//
// CE identity (one-hot gt): ce = w[g] * (log(sum_k exp(p_k)) - p_g), p = softmax(x).
// Dice needs only confusion-matrix marginals -> 24 integer counters.

#define NTHREADS 256
#define SPT 4            // samples per thread per iteration
#define MAXBLOCKS 4096

__global__ void wcd_init(unsigned int* __restrict__ cnt) {
    if (threadIdx.x < 24) cnt[threadIdx.x] = 0u;
}

// Expand 8x4-bit nibble-packed counter into 4 u32s of 2x16-bit fields.
#define EXPAND(n, o0, o1, o2, o3)                                             \
    o0 = ((n) & 0xFu)         | (((n) >> 4)  & 0xFu) << 16;                   \
    o1 = (((n) >> 8) & 0xFu)  | (((n) >> 12) & 0xFu) << 16;                   \
    o2 = (((n) >> 16) & 0xFu) | (((n) >> 20) & 0xFu) << 16;                   \
    o3 = (((n) >> 24) & 0xFu) | (((n) >> 28) & 0xFu) << 16;

__device__ __forceinline__ void process_sample(
    const float4& A0, const float4& A1, const float4& B0, const float4& B1,
    const float* __restrict__ sw, float& ce,
    unsigned int& gt_n, unsigned int& pr_n, unsigned int& tp_n)
{
    float x[8] = {A0.x, A0.y, A0.z, A0.w, A1.x, A1.y, A1.z, A1.w};
    float g[8] = {B0.x, B0.y, B0.z, B0.w, B1.x, B1.y, B1.z, B1.w};

    // argmax(pred) == argmax(softmax(pred)), first occurrence
    float m = x[0]; int am = 0;
    #pragma unroll
    for (int j = 1; j < 8; ++j) { if (x[j] > m) { m = x[j]; am = j; } }

    // one-hot gt class
    int gi = 0;
    #pragma unroll
    for (int j = 1; j < 8; ++j) { if (g[j] > 0.5f) gi = j; }

    // softmax (max-subtracted)
    float e[8], se = 0.0f;
    #pragma unroll
    for (int j = 0; j < 8; ++j) { e[j] = __expf(x[j] - m); se += e[j]; }
    float inv = 1.0f / se;

    // log_softmax(p)[gi]; p in [0,1] so no max-subtraction needed
    float s2 = 0.0f, pg = 0.0f;
    #pragma unroll
    for (int j = 0; j < 8; ++j) {
        float pj = e[j] * inv;
        s2 += __expf(pj);
        if (j == gi) pg = pj;
    }
    ce += sw[gi] * (__logf(s2) - pg);

    gt_n += 1u << (gi << 2);
    pr_n += 1u << (am << 2);
    if (gi == am) tp_n += 1u << (gi << 2);
}

__global__ __launch_bounds__(NTHREADS) void wcd_main(
    const float* __restrict__ pred, const float* __restrict__ gt,
    const float* __restrict__ cw, unsigned int* __restrict__ cnt,
    float* __restrict__ ce_partial, int B)
{
    __shared__ float sw[8];
    __shared__ unsigned int scnt[24];
    __shared__ float sce[NTHREADS / 64];

    const int tid = threadIdx.x;
    if (tid < 8)  sw[tid]   = cw[tid];
    if (tid < 24) scnt[tid] = 0u;
    __syncthreads();

    float ce = 0.0f;
    unsigned int gt_n = 0u, pr_n = 0u, tp_n = 0u;  // nibble counters

    const long long stride = (long long)gridDim.x * blockDim.x;
    const float4* __restrict__ p4 = reinterpret_cast<const float4*>(pred);
    const float4* __restrict__ g4 = reinterpret_cast<const float4*>(gt);

    long long s0 = ((long long)blockIdx.x * blockDim.x + tid) * SPT;

    // ---- main loop (executes exactly once for B = grid*SPT) ----
    for (long long s = s0; s + (SPT - 1) < B; s += stride * SPT) {
        size_t off = 2 * (size_t)s;   // float4 index
        // all 16 loads issued before any compute
        float4 pA[2 * SPT], gA[2 * SPT];
        #pragma unroll
        for (int k = 0; k < 2 * SPT; ++k) pA[k] = p4[off + k];
        #pragma unroll
        for (int k = 0; k < 2 * SPT; ++k) gA[k] = g4[off + k];

        #pragma unroll
        for (int k = 0; k < SPT; ++k)
            process_sample(pA[2 * k], pA[2 * k + 1], gA[2 * k], gA[2 * k + 1],
                           sw, ce, gt_n, pr_n, tp_n);
    }

    // ---- generic tail (no-op for the benchmark shape) ----
    long long tail_start = (B / (stride * SPT)) * (stride * SPT);
    for (long long s = tail_start + (long long)blockIdx.x * blockDim.x + tid;
         s < B; s += stride) {
        if (s < tail_start) continue;
        size_t off = 2 * (size_t)s;
        float4 a0 = p4[off], a1 = p4[off + 1];
        float4 b0 = g4[off], b1 = g4[off + 1];
        process_sample(a0, a1, b0, b1, sw, ce, gt_n, pr_n, tp_n);
    }

    // ---- wave-level reduction (64 lanes), all in registers ----
    unsigned int a0, a1, a2, a3, b0_, b1_, b2_, b3_, c0, c1, c2, c3;
    EXPAND(gt_n, a0, a1, a2, a3);
    EXPAND(pr_n, b0_, b1_, b2_, b3_);
    EXPAND(tp_n, c0, c1, c2, c3);

    #pragma unroll
    for (int msk = 32; msk > 0; msk >>= 1) {
        ce  += __shfl_xor(ce, msk, 64);
        a0  += __shfl_xor(a0, msk, 64);  a1 += __shfl_xor(a1, msk, 64);
        a2  += __shfl_xor(a2, msk, 64);  a3 += __shfl_xor(a3, msk, 64);
        b0_ += __shfl_xor(b0_, msk, 64); b1_ += __shfl_xor(b1_, msk, 64);
        b2_ += __shfl_xor(b2_, msk, 64); b3_ += __shfl_xor(b3_, msk, 64);
        c0  += __shfl_xor(c0, msk, 64);  c1 += __shfl_xor(c1, msk, 64);
        c2  += __shfl_xor(c2, msk, 64);  c3 += __shfl_xor(c3, msk, 64);
    }

    const int lane = tid & 63;
    const int wid  = tid >> 6;
    if (lane == 0) {
        sce[wid] = ce;
        atomicAdd(&scnt[0],  a0 & 0xFFFFu);  atomicAdd(&scnt[1],  a0 >> 16);
        atomicAdd(&scnt[2],  a1 & 0xFFFFu);  atomicAdd(&scnt[3],  a1 >> 16);
        atomicAdd(&scnt[4],  a2 & 0xFFFFu);  atomicAdd(&scnt[5],  a2 >> 16);
        atomicAdd(&scnt[6],  a3 & 0xFFFFu);  atomicAdd(&scnt[7],  a3 >> 16);
        atomicAdd(&scnt[8],  b0_ & 0xFFFFu); atomicAdd(&scnt[9],  b0_ >> 16);
        atomicAdd(&scnt[10], b1_ & 0xFFFFu); atomicAdd(&scnt[11], b1_ >> 16);
        atomicAdd(&scnt[12], b2_ & 0xFFFFu); atomicAdd(&scnt[13], b2_ >> 16);
        atomicAdd(&scnt[14], b3_ & 0xFFFFu); atomicAdd(&scnt[15], b3_ >> 16);
        atomicAdd(&scnt[16], c0 & 0xFFFFu);  atomicAdd(&scnt[17], c0 >> 16);
        atomicAdd(&scnt[18], c1 & 0xFFFFu);  atomicAdd(&scnt[19], c1 >> 16);
        atomicAdd(&scnt[20], c2 & 0xFFFFu);  atomicAdd(&scnt[21], c2 >> 16);
        atomicAdd(&scnt[22], c3 & 0xFFFFu);  atomicAdd(&scnt[23], c3 >> 16);
    }
    __syncthreads();

    if (tid < 24 && scnt[tid] != 0u) atomicAdd(&cnt[tid], scnt[tid]);
    if (tid == 0) {
        float s = 0.0f;
        #pragma unroll
        for (int w = 0; w < NTHREADS / 64; ++w) s += sce[w];
        ce_partial[blockIdx.x] = s;
    }
}

__global__ __launch_bounds__(NTHREADS) void wcd_finalize(
    const unsigned int* __restrict__ cnt, const float* __restrict__ ce_partial,
    const float* __restrict__ cw, float* __restrict__ out, int B, int nblocks)
{
    __shared__ float sred[NTHREADS];
    const int tid = threadIdx.x;
    float s = 0.0f;
    for (int i = tid; i < nblocks; i += NTHREADS) s += ce_partial[i];
    sred[tid] = s;
    __syncthreads();
    #pragma unroll
    for (int k = NTHREADS / 2; k > 0; k >>= 1) {
        if (tid < k) sred[tid] += sred[tid + k];
        __syncthreads();
    }
    if (tid == 0) {
        const float EPS = 1e-8f;
        float dice_loss = 0.0f;
        #pragma unroll
        for (int c = 0; c < 8; ++c) {
            float tp   = (float)cnt[16 + c];
            float rowc = (float)cnt[c];       // tp + fn
            float colc = (float)cnt[8 + c];   // tp + fp
            float dice = (tp + EPS) / (rowc + colc - tp + EPS);
            dice_loss += (1.0f - dice) * cw[c];
        }
        dice_loss *= (1.0f / 8.0f);
        float cce = sred[0] / (float)B;
        out[0] = cce * 1.0f + dice_loss * 0.5f;
    }
}

extern "C" void kernel_launch(void* const* d_in, const int* in_sizes, int n_in,
                              void* d_out, int out_size, void* d_ws, size_t ws_size,
                              hipStream_t stream) {
    const float* pred = (const float*)d_in[0];
    const float* gt   = (const float*)d_in[1];
    const float* cw   = (const float*)d_in[2];
    float* out        = (float*)d_out;

    const int C = in_sizes[2];          // 8
    const int B = in_sizes[0] / C;      // 4194304

    int nblocks = (int)((B + (long long)NTHREADS * SPT - 1) / ((long long)NTHREADS * SPT));
    if (nblocks > MAXBLOCKS) nblocks = MAXBLOCKS;
    if (nblocks < 1) nblocks = 1;

    unsigned int* cnt  = (unsigned int*)d_ws;
    float* ce_partial  = (float*)d_ws + 32;

    wcd_init<<<1, 64, 0, stream>>>(cnt);
    wcd_main<<<nblocks, NTHREADS, 0, stream>>>(pred, gt, cw, cnt, ce_partial, B);
    wcd_finalize<<<1, NTHREADS, 0, stream>>>(cnt, ce_partial, cw, out, B, nblocks);
}

// Round 5
// 61.506 us; speedup vs baseline: 1.4081x; 1.4081x over previous
//
#include <hip/hip_runtime.h>

// WeightedCCEDiceLossWithSoftmax — fused single-pass reduction.
// Round 5: explicit register-prefetch software pipeline. Each thread owns 2
// ADJACENT samples per iteration (round-3 footprint: wave = contiguous 4KB per
// array, FETCH floor 132MB). The NEXT iteration's 8 float4 are loaded into
// named registers BEFORE processing the current pair, with sched_barrier(0)
// pinning the load-issue point so the compiler cannot sink the loads (rounds
// 3/4 showed it does exactly that: VGPR=24/40 instead of the 64/128 needed).
//
// CE identity (one-hot gt): ce = w[g] * (log(sum_k exp(p_k)) - p_g), p = softmax(x).
// Dice needs only confusion-matrix marginals -> 24 integer counters.

#define NBLOCKS 2048
#define NTHREADS 256

__global__ void wcd_init(unsigned int* __restrict__ cnt) {
    if (threadIdx.x < 24) cnt[threadIdx.x] = 0u;
}

// Expand 8x4-bit nibble-packed counter into 4 u32s of 2x16-bit fields.
#define EXPAND(n, o0, o1, o2, o3)                                             \
    o0 = ((n) & 0xFu)         | (((n) >> 4)  & 0xFu) << 16;                   \
    o1 = (((n) >> 8) & 0xFu)  | (((n) >> 12) & 0xFu) << 16;                   \
    o2 = (((n) >> 16) & 0xFu) | (((n) >> 20) & 0xFu) << 16;                   \
    o3 = (((n) >> 24) & 0xFu) | (((n) >> 28) & 0xFu) << 16;

__device__ __forceinline__ void process_sample(
    const float4& A0, const float4& A1, const float4& B0, const float4& B1,
    const float* __restrict__ sw, float& ce,
    unsigned int& gt_n, unsigned int& pr_n, unsigned int& tp_n)
{
    float x[8] = {A0.x, A0.y, A0.z, A0.w, A1.x, A1.y, A1.z, A1.w};
    float g[8] = {B0.x, B0.y, B0.z, B0.w, B1.x, B1.y, B1.z, B1.w};

    // argmax(pred) == argmax(softmax(pred)), first occurrence
    float m = x[0]; int am = 0;
    #pragma unroll
    for (int j = 1; j < 8; ++j) { if (x[j] > m) { m = x[j]; am = j; } }

    // one-hot gt class
    int gi = 0;
    #pragma unroll
    for (int j = 1; j < 8; ++j) { if (g[j] > 0.5f) gi = j; }

    // softmax (max-subtracted)
    float e[8], se = 0.0f;
    #pragma unroll
    for (int j = 0; j < 8; ++j) { e[j] = __expf(x[j] - m); se += e[j]; }
    float inv = 1.0f / se;

    // log_softmax(p)[gi]; p in [0,1] so no max-subtraction needed
    float s2 = 0.0f, pg = 0.0f;
    #pragma unroll
    for (int j = 0; j < 8; ++j) {
        float pj = e[j] * inv;
        s2 += __expf(pj);
        if (j == gi) pg = pj;
    }
    ce += sw[gi] * (__logf(s2) - pg);

    gt_n += 1u << (gi << 2);
    pr_n += 1u << (am << 2);
    if (gi == am) tp_n += 1u << (gi << 2);
}

__global__ __launch_bounds__(NTHREADS) void wcd_main(
    const float* __restrict__ pred, const float* __restrict__ gt,
    const float* __restrict__ cw, unsigned int* __restrict__ cnt,
    float* __restrict__ ce_partial, int B)
{
    __shared__ float sw[8];
    __shared__ unsigned int scnt[24];
    __shared__ float sce[NTHREADS / 64];

    const int tid = threadIdx.x;
    if (tid < 8)  sw[tid]   = cw[tid];
    if (tid < 24) scnt[tid] = 0u;
    __syncthreads();

    float ce = 0.0f;
    unsigned int gt_n = 0u, pr_n = 0u, tp_n = 0u;  // nibble counters

    const long long stride = (long long)gridDim.x * blockDim.x;
    const float4* __restrict__ p4 = reinterpret_cast<const float4*>(pred);
    const float4* __restrict__ g4 = reinterpret_cast<const float4*>(gt);

    long long j = (long long)blockIdx.x * blockDim.x + tid;  // pair index

    if (2 * j + 1 < B) {
        // prologue: load current pair
        size_t off = 4 * (size_t)j;
        float4 cp0 = p4[off], cp1 = p4[off + 1], cp2 = p4[off + 2], cp3 = p4[off + 3];
        float4 cg0 = g4[off], cg1 = g4[off + 1], cg2 = g4[off + 2], cg3 = g4[off + 3];

        long long jn = j + stride;
        for (; 2 * jn + 1 < B; jn += stride) {
            // issue next pair's loads into named prefetch registers
            size_t offn = 4 * (size_t)jn;
            float4 np0 = p4[offn], np1 = p4[offn + 1], np2 = p4[offn + 2], np3 = p4[offn + 3];
            float4 ng0 = g4[offn], ng1 = g4[offn + 1], ng2 = g4[offn + 2], ng3 = g4[offn + 3];
            // pin the issue point: nothing may move across this barrier
            __builtin_amdgcn_sched_barrier(0);

            process_sample(cp0, cp1, cg0, cg1, sw, ce, gt_n, pr_n, tp_n);
            process_sample(cp2, cp3, cg2, cg3, sw, ce, gt_n, pr_n, tp_n);

            cp0 = np0; cp1 = np1; cp2 = np2; cp3 = np3;
            cg0 = ng0; cg1 = ng1; cg2 = ng2; cg3 = ng3;
        }
        // epilogue: process last loaded pair
        process_sample(cp0, cp1, cg0, cg1, sw, ce, gt_n, pr_n, tp_n);
        process_sample(cp2, cp3, cg2, cg3, sw, ce, gt_n, pr_n, tp_n);
        j = jn;
    }
    if (2 * j < B) {   // odd-B tail: single sample 2j
        size_t off = 4 * (size_t)j;
        float4 a0 = p4[off], a1 = p4[off + 1];
        float4 b0 = g4[off], b1 = g4[off + 1];
        process_sample(a0, a1, b0, b1, sw, ce, gt_n, pr_n, tp_n);
    }

    // ---- wave-level reduction (64 lanes), all in registers ----
    unsigned int a0, a1, a2, a3, b0_, b1_, b2_, b3_, c0, c1, c2, c3;
    EXPAND(gt_n, a0, a1, a2, a3);
    EXPAND(pr_n, b0_, b1_, b2_, b3_);
    EXPAND(tp_n, c0, c1, c2, c3);

    #pragma unroll
    for (int msk = 32; msk > 0; msk >>= 1) {
        ce  += __shfl_xor(ce, msk, 64);
        a0  += __shfl_xor(a0, msk, 64);  a1 += __shfl_xor(a1, msk, 64);
        a2  += __shfl_xor(a2, msk, 64);  a3 += __shfl_xor(a3, msk, 64);
        b0_ += __shfl_xor(b0_, msk, 64); b1_ += __shfl_xor(b1_, msk, 64);
        b2_ += __shfl_xor(b2_, msk, 64); b3_ += __shfl_xor(b3_, msk, 64);
        c0  += __shfl_xor(c0, msk, 64);  c1 += __shfl_xor(c1, msk, 64);
        c2  += __shfl_xor(c2, msk, 64);  c3 += __shfl_xor(c3, msk, 64);
    }

    const int lane = tid & 63;
    const int wid  = tid >> 6;
    if (lane == 0) {
        sce[wid] = ce;
        atomicAdd(&scnt[0],  a0 & 0xFFFFu);  atomicAdd(&scnt[1],  a0 >> 16);
        atomicAdd(&scnt[2],  a1 & 0xFFFFu);  atomicAdd(&scnt[3],  a1 >> 16);
        atomicAdd(&scnt[4],  a2 & 0xFFFFu);  atomicAdd(&scnt[5],  a2 >> 16);
        atomicAdd(&scnt[6],  a3 & 0xFFFFu);  atomicAdd(&scnt[7],  a3 >> 16);
        atomicAdd(&scnt[8],  b0_ & 0xFFFFu); atomicAdd(&scnt[9],  b0_ >> 16);
        atomicAdd(&scnt[10], b1_ & 0xFFFFu); atomicAdd(&scnt[11], b1_ >> 16);
        atomicAdd(&scnt[12], b2_ & 0xFFFFu); atomicAdd(&scnt[13], b2_ >> 16);
        atomicAdd(&scnt[14], b3_ & 0xFFFFu); atomicAdd(&scnt[15], b3_ >> 16);
        atomicAdd(&scnt[16], c0 & 0xFFFFu);  atomicAdd(&scnt[17], c0 >> 16);
        atomicAdd(&scnt[18], c1 & 0xFFFFu);  atomicAdd(&scnt[19], c1 >> 16);
        atomicAdd(&scnt[20], c2 & 0xFFFFu);  atomicAdd(&scnt[21], c2 >> 16);
        atomicAdd(&scnt[22], c3 & 0xFFFFu);  atomicAdd(&scnt[23], c3 >> 16);
    }
    __syncthreads();

    if (tid < 24 && scnt[tid] != 0u) atomicAdd(&cnt[tid], scnt[tid]);
    if (tid == 0) {
        float s = 0.0f;
        #pragma unroll
        for (int w = 0; w < NTHREADS / 64; ++w) s += sce[w];
        ce_partial[blockIdx.x] = s;
    }
}

__global__ __launch_bounds__(NTHREADS) void wcd_finalize(
    const unsigned int* __restrict__ cnt, const float* __restrict__ ce_partial,
    const float* __restrict__ cw, float* __restrict__ out, int B)
{
    __shared__ float sred[NTHREADS];
    const int tid = threadIdx.x;
    float s = 0.0f;
    for (int i = tid; i < NBLOCKS; i += NTHREADS) s += ce_partial[i];
    sred[tid] = s;
    __syncthreads();
    #pragma unroll
    for (int k = NTHREADS / 2; k > 0; k >>= 1) {
        if (tid < k) sred[tid] += sred[tid + k];
        __syncthreads();
    }
    if (tid == 0) {
        const float EPS = 1e-8f;
        float dice_loss = 0.0f;
        #pragma unroll
        for (int c = 0; c < 8; ++c) {
            float tp   = (float)cnt[16 + c];
            float rowc = (float)cnt[c];       // tp + fn
            float colc = (float)cnt[8 + c];   // tp + fp
            float dice = (tp + EPS) / (rowc + colc - tp + EPS);
            dice_loss += (1.0f - dice) * cw[c];
        }
        dice_loss *= (1.0f / 8.0f);
        float cce = sred[0] / (float)B;
        out[0] = cce * 1.0f + dice_loss * 0.5f;
    }
}

extern "C" void kernel_launch(void* const* d_in, const int* in_sizes, int n_in,
                              void* d_out, int out_size, void* d_ws, size_t ws_size,
                              hipStream_t stream) {
    const float* pred = (const float*)d_in[0];
    const float* gt   = (const float*)d_in[1];
    const float* cw   = (const float*)d_in[2];
    float* out        = (float*)d_out;

    const int C = in_sizes[2];          // 8
    const int B = in_sizes[0] / C;      // 4194304

    unsigned int* cnt  = (unsigned int*)d_ws;
    float* ce_partial  = (float*)d_ws + 32;

    wcd_init<<<1, 64, 0, stream>>>(cnt);
    wcd_main<<<NBLOCKS, NTHREADS, 0, stream>>>(pred, gt, cw, cnt, ce_partial, B);
    wcd_finalize<<<1, NTHREADS, 0, stream>>>(cnt, ce_partial, cw, out, B);
}